// Round 3
// baseline (4118.014 us; speedup 1.0000x reference)
//
#include <hip/hip_runtime.h>
#include <hip/hip_bf16.h>
#include <stdint.h>

// ---------------------------------------------------------------------------
// QLSTM  (T=512, B=64, D=1024, H=1024)
//   Phase 1: Gx = x @ Wx + b      -- parallel bf16 MFMA GEMM [32768x1024]@[1024x4096]
//   Phase 2: persistent kernel, 512 steps:
//              gates = Gx[t] + h @ Wh   (Wh B-fragments resident in REGISTERS)
//              c = f*c + i*g ; h = o*tanh(c)   (fp32 state in registers)
//   Round-3 protocol: self-verifying tagged h words.  Each h element is a u32
//   (tag<<16 | bf16).  Producers fire-and-forget relaxed sc1 stores (no drain,
//   no flags).  Consumers' refill loads ARE the poll: retry until every tag in
//   the thread's slice equals t+1.  One barrier per step (h LDS tile is
//   double-buffered, so no WAR barrier needed).
// ---------------------------------------------------------------------------

typedef unsigned short u16;
typedef unsigned int u32;
typedef unsigned long long u64;
typedef __attribute__((ext_vector_type(8))) short s16x8;   // bf16x8 MFMA frag (4 VGPRs)
typedef __attribute__((ext_vector_type(4))) float f32x4;   // MFMA accumulator

static constexpr int T_ = 512, B_ = 64, D_ = 1024, H_ = 1024;
static constexpr int MX_ = T_ * B_;      // 32768 rows of x_flat
static constexpr int NG_ = 4 * H_;       // 4096 gate cols

__device__ __forceinline__ u16 f2bf(float f) {
  union { __hip_bfloat16 b; u16 u; } v;
  v.b = __float2bfloat16(f);
  return v.u;
}
__device__ __forceinline__ float bf2f(u16 u) {
  union { __hip_bfloat16 b; u16 u; } v;
  v.u = u;
  return __bfloat162float(v.b);
}

__device__ __forceinline__ void gload_lds16(const u16* g, u16* l) {
  __builtin_amdgcn_global_load_lds(
      (const __attribute__((address_space(1))) unsigned int*)(g),
      (__attribute__((address_space(3))) unsigned int*)(l), 16, 0, 0);
}

__device__ __forceinline__ float sigm(float x) {
  return __builtin_amdgcn_rcpf(1.f + __expf(-x));
}
__device__ __forceinline__ float tanh_(float x) {
  return 2.f * __builtin_amdgcn_rcpf(1.f + __expf(-2.f * x)) - 1.f;
}

__device__ __forceinline__ float gxload(const float* p) { return *p; }
__device__ __forceinline__ float gxload(const u16* p) { return bf2f(*p); }
__device__ __forceinline__ void gxstore(float* p, float v) { *p = v; }
__device__ __forceinline__ void gxstore(u16* p, float v) { *p = f2bf(v); }

// ---------------------------------------------------------------------------
// x (fp32) -> bf16, 8 elems/thread
__global__ __launch_bounds__(256) void k_cast_x(const float* __restrict__ x,
                                                u16* __restrict__ xb) {
  size_t i = ((size_t)blockIdx.x * 256 + threadIdx.x) * 8;
  const float4* xp = (const float4*)(x + i);
  float4 a = xp[0], b = xp[1];
  s16x8 o;
  o[0] = (short)f2bf(a.x); o[1] = (short)f2bf(a.y);
  o[2] = (short)f2bf(a.z); o[3] = (short)f2bf(a.w);
  o[4] = (short)f2bf(b.x); o[5] = (short)f2bf(b.y);
  o[6] = (short)f2bf(b.z); o[7] = (short)f2bf(b.w);
  *(s16x8*)(xb + i) = o;
}

// ---------------------------------------------------------------------------
// Weight prep (unchanged; mapping verified by passing bench):
//  wxt [4096 n][1024 k] bf16 :  wxt[n][k] = W_{n>>10}[k][n&1023]
//  whr [64 g][64 c][1024 k] bf16, c: gate=c&3, hcol_local=(c>>4)*4+((c>>2)&3)
//  biasf [4096] fp32
__global__ __launch_bounds__(256) void k_prep_w(
    const float* __restrict__ Wf, const float* __restrict__ Wi,
    const float* __restrict__ Wg, const float* __restrict__ Wo,
    const float* __restrict__ bf_, const float* __restrict__ bi_,
    const float* __restrict__ bg_, const float* __restrict__ bo_,
    u16* __restrict__ wxt, u16* __restrict__ whr, float* __restrict__ biasf) {
  const int bid = blockIdx.x;            // 0..4095
  const int t = threadIdx.x;
  const float* Ws[4] = {Wf, Wi, Wg, Wo};
  {
    const float* src = Ws[bid >> 10];
    const int col = bid & 1023;
#pragma unroll
    for (int it = 0; it < 4; ++it) {
      int k = t + it * 256;
      wxt[(size_t)bid * 1024 + k] = f2bf(src[(size_t)k * 1024 + col]);
    }
  }
  {
    const int g = bid >> 6, c = bid & 63;
    const float* src = Ws[c & 3];
    const int col = g * 16 + ((c >> 4) << 2) + ((c >> 2) & 3);
#pragma unroll
    for (int it = 0; it < 4; ++it) {
      int k = t + it * 256;
      whr[(size_t)bid * 1024 + k] = f2bf(src[(size_t)(1024 + k) * 1024 + col]);
    }
  }
  if (t == 0) {
    const float* bs[4] = {bf_, bi_, bg_, bo_};
    biasf[bid] = bs[bid >> 10][bid & 1023];
  }
}

// ---------------------------------------------------------------------------
// Gx = x_bf16 @ WxT^T + bias.  m97-style 128x128 tile, BK=32, 256 threads.
template <typename GT>
__global__ __launch_bounds__(256) void k_gemm_gx(
    const u16* __restrict__ A,    // [32768][1024]
    const u16* __restrict__ Bt,   // [4096][1024]
    const float* __restrict__ biasf,
    GT* __restrict__ C) {         // [32768][4096]
  __shared__ u16 aLds[128 * 32];
  __shared__ u16 bLds[128 * 32];
  const int tid = threadIdx.x;
  const int w = tid >> 6, l = tid & 63;
  const int q = l >> 4, cc = l & 15;
  const int bm = blockIdx.x, bn = blockIdx.y;
  const int wm = (w & 1) * 64, wn = (w >> 1) * 64;
  const int lrow = l >> 2, lchunk = (l & 3) * 8;

  f32x4 zero = {0.f, 0.f, 0.f, 0.f};
  f32x4 acc[4][4];
#pragma unroll
  for (int i = 0; i < 4; ++i)
#pragma unroll
    for (int j = 0; j < 4; ++j) acc[i][j] = zero;

  for (int k0 = 0; k0 < 1024; k0 += 32) {
#pragma unroll
    for (int r = 0; r < 2; ++r) {
      gload_lds16(A + (size_t)(bm * 128 + r * 64 + w * 16 + lrow) * 1024 + k0 + lchunk,
                  &aLds[(r * 64 + w * 16) * 32]);
      gload_lds16(Bt + (size_t)(bn * 128 + r * 64 + w * 16 + lrow) * 1024 + k0 + lchunk,
                  &bLds[(r * 64 + w * 16) * 32]);
    }
    __syncthreads();
    s16x8 af[4], bf[4];
#pragma unroll
    for (int i = 0; i < 4; ++i)
      af[i] = *(const s16x8*)&aLds[(wm + i * 16 + cc) * 32 + q * 8];
#pragma unroll
    for (int j = 0; j < 4; ++j)
      bf[j] = *(const s16x8*)&bLds[(wn + j * 16 + cc) * 32 + q * 8];
#pragma unroll
    for (int i = 0; i < 4; ++i)
#pragma unroll
      for (int j = 0; j < 4; ++j)
        acc[i][j] = __builtin_amdgcn_mfma_f32_16x16x32_bf16(af[i], bf[j], acc[i][j], 0, 0, 0);
    __syncthreads();
  }
#pragma unroll
  for (int i = 0; i < 4; ++i) {
    const int row0 = bm * 128 + wm + i * 16 + q * 4;
#pragma unroll
    for (int j = 0; j < 4; ++j) {
      const int col = bn * 128 + wn + j * 16 + cc;
      const float bb = biasf[col];
#pragma unroll
      for (int r = 0; r < 4; ++r)
        gxstore(C + (size_t)(row0 + r) * 4096 + col, acc[i][j][r] + bb);
    }
  }
}

// ---------------------------------------------------------------------------
// Persistent recurrent kernel. 256 blocks x 256 threads, 64KB LDS.
// block: m = bid>>6 (batch tile of 16), g = bid&63 (16 h-cols -> 64 gate cols).
// hbuf: [2][64 rows][1024 cols] u32 tagged words (tag<<16 | bf16 h).
template <typename GT>
__global__ __launch_bounds__(256, 1) void k_lstm(
    const u16* __restrict__ Whr,   // [64][64][1024]
    const GT* __restrict__ Gx,     // [32768][4096]
    u32* __restrict__ hbuf,        // [2][64][1024] tagged (zeroed: tag0 = h0)
    float* __restrict__ out) {     // stacked [512][64][1024], hT, cT
  // double-buffered packed h tile: 2 x 16 rows x 1024 cols bf16, chunk-swizzled
  // (16B chunk p of row r stored at LDS chunk p ^ (r&7) within the row).
  __shared__ u16 hl[2 * 16 * 1024];            // 64 KB
  const int tid = threadIdx.x;
  const int w = tid >> 6, l = tid & 63, q = l >> 4, cc = l & 15;
  const int m = blockIdx.x >> 6, g = blockIdx.x & 63;
  const int gate = cc & 3;
  const int hcol = g * 16 + w * 4 + (cc >> 2);
  const int gxcol = gate * 1024 + hcol;
  const int wcol = w * 16 + cc;                // this lane's B-frag column

  // ---- Wh B-fragments resident in registers (128 VGPRs/lane) ----
  // bfr[kk] = whr[(g*64 + wcol)*1024 + kk*32 + q*8 .. +8]  (identical values
  // to the old LDS-staged BFRAG(kk); one-time global load).
  s16x8 bfr[32];
  {
    const u16* src = Whr + (size_t)(g * 64 + wcol) * 1024 + q * 8;
#pragma unroll
    for (int kk = 0; kk < 32; ++kk)
      bfr[kk] = *(const s16x8*)(src + kk * 32);
  }

  // per-lane swizzled A-frag read offsets (u16 units, relative to buffer base)
  const int xbit = (cc >> 2) & 1;
  const int off0 = cc * 1024 + ((q ^ (cc & 3)) + 4 * xbit) * 8;       // even frags
  const int off1 = cc * 1024 + ((q ^ (cc & 3)) + 4 * (1 - xbit)) * 8; // odd frags

  // refill geometry: thread owns packed chunks c = s*256 + tid (s=0..7):
  //   row r = 2s + (tid>>7), col-chunk p = tid&127  (8 cols = 1 producer)
  const int rbase = tid >> 7;
  const int p = tid & 127;
  const int p2 = p * 4;                        // u64 index of col p*8 within row

  int dead = 0;

  // poll-refill: load tagged u64s, retry until every tag == tag, pack -> LDS
  auto refill = [&](int buf, unsigned tag) {
    const u64* base = (const u64*)(hbuf + (size_t)buf * (B_ * H_) +
                                   (size_t)m * 16 * 1024);
    u64 v[32];
#pragma unroll
    for (int s = 0; s < 8; ++s) {
      const u64* ap = base + (2 * s + rbase) * 512 + p2;
#pragma unroll
      for (int j = 0; j < 4; ++j)
        v[s * 4 + j] = __hip_atomic_load(ap + j, __ATOMIC_RELAXED,
                                         __HIP_MEMORY_SCOPE_AGENT);
    }
    const u64 want = ((u64)tag << 48) | ((u64)tag << 16);
    const u64 msk = 0xFFFF0000FFFF0000ull;
    for (unsigned it = 0;; ++it) {
      u64 bad = 0;
#pragma unroll
      for (int i = 0; i < 32; ++i) bad |= (v[i] ^ want);
      if (((bad & msk) == 0) | dead) break;
      if (it > (1u << 17)) { dead = 1; break; }   // safety: no hangs
      __builtin_amdgcn_s_sleep(1);
#pragma unroll
      for (int s = 0; s < 8; ++s) {
        const u64* ap = base + (2 * s + rbase) * 512 + p2;
#pragma unroll
        for (int j = 0; j < 4; ++j)
          v[s * 4 + j] = __hip_atomic_load(ap + j, __ATOMIC_RELAXED,
                                           __HIP_MEMORY_SCOPE_AGENT);
      }
    }
    u16* dst = hl + buf * (16 * 1024);
#pragma unroll
    for (int s = 0; s < 8; ++s) {
      const int r = 2 * s + rbase;
      const int J = r * 128 + (p ^ (r & 7));
      u32 wv[4];
#pragma unroll
      for (int j = 0; j < 4; ++j) {
        u64 x = v[s * 4 + j];
        wv[j] = (u32)(x & 0xFFFFu) | ((u32)(x >> 16) & 0xFFFF0000u);
      }
      *(s16x8*)(dst + J * 8) = *(const s16x8*)wv;
    }
  };

  float cst[4] = {0.f, 0.f, 0.f, 0.f};
  float hlast[4] = {0.f, 0.f, 0.f, 0.f};

  // prefetch Gx for t=0
  float gxv[4];
  {
    const GT* gp = Gx + (size_t)(m * 16 + q * 4) * 4096 + gxcol;
#pragma unroll
    for (int r = 0; r < 4; ++r) gxv[r] = gxload(gp + (size_t)r * 4096);
  }

  refill(0, 0);         // h0 tile: hbuf[0] zeroed -> tag 0, h = 0
  __syncthreads();      // hl[0] ready

  for (int t = 0; t < T_; ++t) {
    const u16* hbase = hl + (t & 1) * (16 * 1024);
    f32x4 acc0 = {0.f, 0.f, 0.f, 0.f}, acc1 = {0.f, 0.f, 0.f, 0.f};
#pragma unroll
    for (int I = 0; I < 32; I += 2) {
      s16x8 a0 = *(const s16x8*)(hbase + off0 + (I >> 1) * 64);
      s16x8 a1 = *(const s16x8*)(hbase + off1 + (I >> 1) * 64);
      acc0 = __builtin_amdgcn_mfma_f32_16x16x32_bf16(a0, bfr[I], acc0, 0, 0, 0);
      acc1 = __builtin_amdgcn_mfma_f32_16x16x32_bf16(a1, bfr[I + 1], acc1, 0, 0, 0);
    }

    float v0[4];
#pragma unroll
    for (int r = 0; r < 4; ++r) {
      float x = acc0[r] + acc1[r] + gxv[r];
      v0[r] = (gate == 2) ? tanh_(x) : sigm(x);
    }
#pragma unroll
    for (int r = 0; r < 4; ++r) {
      float a0 = v0[r];
      float a1 = __shfl_xor(a0, 1);
      float a2 = __shfl_xor(a0, 2);
      float a3 = __shfl_xor(a1, 2);
      float fv = (gate == 0) ? a0 : (gate == 1) ? a1 : (gate == 2) ? a2 : a3;
      float iv = (gate == 0) ? a1 : (gate == 1) ? a0 : (gate == 2) ? a3 : a2;
      float gv = (gate == 0) ? a2 : (gate == 1) ? a3 : (gate == 2) ? a0 : a1;
      float ov = (gate == 0) ? a3 : (gate == 1) ? a2 : (gate == 2) ? a1 : a0;
      float cn = fv * cst[r] + iv * gv;
      cst[r] = cn;
      hlast[r] = ov * tanh_(cn);
    }

    const int nb = (t + 1) & 1;
    const bool last = (t + 1 == T_);

    // ---- tagged h publish: fire-and-forget relaxed sc1 stores ----
    if (!last && gate == 0) {
      u32* hd = hbuf + (size_t)nb * (B_ * H_);
      const u32 tagw = (u32)(t + 1) << 16;
#pragma unroll
      for (int r = 0; r < 4; ++r) {
        const int row = m * 16 + q * 4 + r;
        __hip_atomic_store(hd + row * 1024 + hcol, tagw | (u32)f2bf(hlast[r]),
                           __ATOMIC_RELAXED, __HIP_MEMORY_SCOPE_AGENT);
      }
    }

    // Gx prefetch for t+1 and stacked-h output: issue now, drain under poll
    float gxn[4];
    {
      const int tn = (t + 1) & 511;
      const GT* gp = Gx + (size_t)(tn * 64 + m * 16 + q * 4) * 4096 + gxcol;
#pragma unroll
      for (int r = 0; r < 4; ++r) gxn[r] = gxload(gp + (size_t)r * 4096);
    }
    if (gate == 0) {
#pragma unroll
      for (int r = 0; r < 4; ++r) {
        const int row = m * 16 + q * 4 + r;
        out[(size_t)(t * 64 + row) * 1024 + hcol] = hlast[r];
      }
    }

    // ---- poll-refill for t+1 into the OTHER hl buffer (no WAR: dbuf) ----
    if (!last) refill(nb, (unsigned)(t + 1));
    __syncthreads();   // hl[nb] ready; drains gx loads / out stores under poll

#pragma unroll
    for (int r = 0; r < 4; ++r) gxv[r] = gxn[r];
  }

  if (gate == 0) {
    float* hT = out + (size_t)T_ * B_ * H_;
    float* cT = hT + B_ * H_;
#pragma unroll
    for (int r = 0; r < 4; ++r) {
      const int row = m * 16 + q * 4 + r;
      hT[row * 1024 + hcol] = hlast[r];
      cT[row * 1024 + hcol] = cst[r];
    }
  }
}

// ---------------------------------------------------------------------------
extern "C" void kernel_launch(void* const* d_in, const int* in_sizes, int n_in,
                              void* d_out, int out_size, void* d_ws, size_t ws_size,
                              hipStream_t stream) {
  (void)in_sizes; (void)n_in; (void)out_size;
  const float* x   = (const float*)d_in[0];
  const float* Wf  = (const float*)d_in[1];
  const float* bf_ = (const float*)d_in[2];
  const float* Wi  = (const float*)d_in[3];
  const float* bi_ = (const float*)d_in[4];
  const float* Wg  = (const float*)d_in[5];
  const float* bg_ = (const float*)d_in[6];
  const float* Wo  = (const float*)d_in[7];
  const float* bo_ = (const float*)d_in[8];
  float* out = (float*)d_out;

  uint8_t* ws = (uint8_t*)d_ws;
  const size_t n_gx    = (size_t)MX_ * NG_;
  const size_t sz_xb   = (size_t)MX_ * 1024 * 2;   // 64 MB
  const size_t sz_wxt  = (size_t)4096 * 1024 * 2;  // 8 MB
  const size_t sz_whr  = (size_t)4096 * 1024 * 2;  // 8 MB
  const size_t sz_bias = 4096 * 4;
  const size_t sz_hbuf = (size_t)2 * 64 * 1024 * 4;  // 512 KB tagged u32
  const size_t fixed = sz_xb + sz_wxt + sz_whr + sz_bias + sz_hbuf + 1024;
  const bool f32gx = ws_size >= fixed + n_gx * 4;  // fp32 Gx (512 MB) if it fits
  const size_t sz_gx = n_gx * (f32gx ? 4 : 2);

  size_t off = 0;
  uint8_t* p_gx   = ws;                  off += sz_gx;
  u16*     xb     = (u16*)(ws + off);    off += sz_xb;
  u16*     wxt    = (u16*)(ws + off);    off += sz_wxt;
  u16*     whr    = (u16*)(ws + off);    off += sz_whr;
  float*   biasf  = (float*)(ws + off);  off += sz_bias;
  u32*     hbuf   = (u32*)(ws + off);

  // zero tagged h buffers: tag 0 in buf0 == valid h0 (= 0)
  hipMemsetAsync(hbuf, 0, sz_hbuf, stream);
  k_cast_x<<<(MX_ * 1024) / (256 * 8), 256, 0, stream>>>(x, xb);
  k_prep_w<<<4096, 256, 0, stream>>>(Wf, Wi, Wg, Wo, bf_, bi_, bg_, bo_, wxt, whr, biasf);
  if (f32gx) {
    k_gemm_gx<float><<<dim3(256, 32), 256, 0, stream>>>(xb, wxt, biasf, (float*)p_gx);
    k_lstm<float><<<256, 256, 0, stream>>>(whr, (const float*)p_gx, hbuf, out);
  } else {
    k_gemm_gx<u16><<<dim3(256, 32), 256, 0, stream>>>(xb, wxt, biasf, (u16*)p_gx);
    k_lstm<u16><<<256, 256, 0, stream>>>(whr, (const u16*)p_gx, hbuf, out);
  }
}

// Round 5
// 2355.170 us; speedup vs baseline: 1.7485x; 1.7485x over previous
//
#include <hip/hip_runtime.h>
#include <hip/hip_bf16.h>
#include <stdint.h>

// ---------------------------------------------------------------------------
// QLSTM  (T=512, B=64, D=1024, H=1024)
//   Phase 1: Gx = x @ Wx + b      -- parallel bf16 MFMA GEMM [32768x1024]@[1024x4096]
//   Phase 2: persistent kernel, 512 steps:
//              gates = Gx[t] + h @ Wh   (Wh B-fragments resident in REGISTERS)
//              c = f*c + i*g ; h = o*tanh(c)   (fp32 state in registers)
//   Round-4 protocol (round-1 skeleton, validated at 1887us, + r3's reg-Wh):
//     - h publish: relaxed/AGENT (sc1) u16 stores, __syncthreads drains vmcnt
//     - tid0 publishes per-block flag (relaxed, 128B-padded line)
//     - ALL waves poll the 64 group flags (lane l -> flag l); no broadcast
//       barrier needed after poll (hl is double-buffered)
//     - cooperative 32KB swizzled refill via relaxed/AGENT u64 loads
//       (mandatory: one 128B line spans 4 producers on different XCDs)
//     - 2 barriers/step (was 3), no per-step ACQUIRE (no cache-inv)
// ---------------------------------------------------------------------------

typedef unsigned short u16;
typedef unsigned int u32;
typedef unsigned long long u64;
typedef __attribute__((ext_vector_type(8))) short s16x8;   // bf16x8 MFMA frag (4 VGPRs)
typedef __attribute__((ext_vector_type(4))) float f32x4;   // MFMA accumulator

static constexpr int T_ = 512, B_ = 64, D_ = 1024, H_ = 1024;
static constexpr int MX_ = T_ * B_;      // 32768 rows of x_flat
static constexpr int NG_ = 4 * H_;       // 4096 gate cols

__device__ __forceinline__ u16 f2bf(float f) {
  union { __hip_bfloat16 b; u16 u; } v;
  v.b = __float2bfloat16(f);
  return v.u;
}
__device__ __forceinline__ float bf2f(u16 u) {
  union { __hip_bfloat16 b; u16 u; } v;
  v.u = u;
  return __bfloat162float(v.b);
}

__device__ __forceinline__ void gload_lds16(const u16* g, u16* l) {
  __builtin_amdgcn_global_load_lds(
      (const __attribute__((address_space(1))) unsigned int*)(g),
      (__attribute__((address_space(3))) unsigned int*)(l), 16, 0, 0);
}

__device__ __forceinline__ float sigm(float x) {
  return __builtin_amdgcn_rcpf(1.f + __expf(-x));
}
__device__ __forceinline__ float tanh_(float x) {
  return 2.f * __builtin_amdgcn_rcpf(1.f + __expf(-2.f * x)) - 1.f;
}

__device__ __forceinline__ float gxload(const float* p) { return *p; }
__device__ __forceinline__ float gxload(const u16* p) { return bf2f(*p); }
__device__ __forceinline__ void gxstore(float* p, float v) { *p = v; }
__device__ __forceinline__ void gxstore(u16* p, float v) { *p = f2bf(v); }

// ---------------------------------------------------------------------------
// x (fp32) -> bf16, 8 elems/thread
__global__ __launch_bounds__(256) void k_cast_x(const float* __restrict__ x,
                                                u16* __restrict__ xb) {
  size_t i = ((size_t)blockIdx.x * 256 + threadIdx.x) * 8;
  const float4* xp = (const float4*)(x + i);
  float4 a = xp[0], b = xp[1];
  s16x8 o;
  o[0] = (short)f2bf(a.x); o[1] = (short)f2bf(a.y);
  o[2] = (short)f2bf(a.z); o[3] = (short)f2bf(a.w);
  o[4] = (short)f2bf(b.x); o[5] = (short)f2bf(b.y);
  o[6] = (short)f2bf(b.z); o[7] = (short)f2bf(b.w);
  *(s16x8*)(xb + i) = o;
}

// ---------------------------------------------------------------------------
// Weight prep (unchanged; mapping verified by passing bench):
//  wxt [4096 n][1024 k] bf16 :  wxt[n][k] = W_{n>>10}[k][n&1023]
//  whr [64 g][64 c][1024 k] bf16, c: gate=c&3, hcol_local=(c>>4)*4+((c>>2)&3)
//  biasf [4096] fp32
__global__ __launch_bounds__(256) void k_prep_w(
    const float* __restrict__ Wf, const float* __restrict__ Wi,
    const float* __restrict__ Wg, const float* __restrict__ Wo,
    const float* __restrict__ bf_, const float* __restrict__ bi_,
    const float* __restrict__ bg_, const float* __restrict__ bo_,
    u16* __restrict__ wxt, u16* __restrict__ whr, float* __restrict__ biasf) {
  const int bid = blockIdx.x;            // 0..4095
  const int t = threadIdx.x;
  const float* Ws[4] = {Wf, Wi, Wg, Wo};
  {
    const float* src = Ws[bid >> 10];
    const int col = bid & 1023;
#pragma unroll
    for (int it = 0; it < 4; ++it) {
      int k = t + it * 256;
      wxt[(size_t)bid * 1024 + k] = f2bf(src[(size_t)k * 1024 + col]);
    }
  }
  {
    const int g = bid >> 6, c = bid & 63;
    const float* src = Ws[c & 3];
    const int col = g * 16 + ((c >> 4) << 2) + ((c >> 2) & 3);
#pragma unroll
    for (int it = 0; it < 4; ++it) {
      int k = t + it * 256;
      whr[(size_t)bid * 1024 + k] = f2bf(src[(size_t)(1024 + k) * 1024 + col]);
    }
  }
  if (t == 0) {
    const float* bs[4] = {bf_, bi_, bg_, bo_};
    biasf[bid] = bs[bid >> 10][bid & 1023];
  }
}

// ---------------------------------------------------------------------------
// Gx = x_bf16 @ WxT^T + bias.  m97-style 128x128 tile, BK=32, 256 threads.
template <typename GT>
__global__ __launch_bounds__(256) void k_gemm_gx(
    const u16* __restrict__ A,    // [32768][1024]
    const u16* __restrict__ Bt,   // [4096][1024]
    const float* __restrict__ biasf,
    GT* __restrict__ C) {         // [32768][4096]
  __shared__ u16 aLds[128 * 32];
  __shared__ u16 bLds[128 * 32];
  const int tid = threadIdx.x;
  const int w = tid >> 6, l = tid & 63;
  const int q = l >> 4, cc = l & 15;
  const int bm = blockIdx.x, bn = blockIdx.y;
  const int wm = (w & 1) * 64, wn = (w >> 1) * 64;
  const int lrow = l >> 2, lchunk = (l & 3) * 8;

  f32x4 zero = {0.f, 0.f, 0.f, 0.f};
  f32x4 acc[4][4];
#pragma unroll
  for (int i = 0; i < 4; ++i)
#pragma unroll
    for (int j = 0; j < 4; ++j) acc[i][j] = zero;

  for (int k0 = 0; k0 < 1024; k0 += 32) {
#pragma unroll
    for (int r = 0; r < 2; ++r) {
      gload_lds16(A + (size_t)(bm * 128 + r * 64 + w * 16 + lrow) * 1024 + k0 + lchunk,
                  &aLds[(r * 64 + w * 16) * 32]);
      gload_lds16(Bt + (size_t)(bn * 128 + r * 64 + w * 16 + lrow) * 1024 + k0 + lchunk,
                  &bLds[(r * 64 + w * 16) * 32]);
    }
    __syncthreads();
    s16x8 af[4], bf[4];
#pragma unroll
    for (int i = 0; i < 4; ++i)
      af[i] = *(const s16x8*)&aLds[(wm + i * 16 + cc) * 32 + q * 8];
#pragma unroll
    for (int j = 0; j < 4; ++j)
      bf[j] = *(const s16x8*)&bLds[(wn + j * 16 + cc) * 32 + q * 8];
#pragma unroll
    for (int i = 0; i < 4; ++i)
#pragma unroll
      for (int j = 0; j < 4; ++j)
        acc[i][j] = __builtin_amdgcn_mfma_f32_16x16x32_bf16(af[i], bf[j], acc[i][j], 0, 0, 0);
    __syncthreads();
  }
#pragma unroll
  for (int i = 0; i < 4; ++i) {
    const int row0 = bm * 128 + wm + i * 16 + q * 4;
#pragma unroll
    for (int j = 0; j < 4; ++j) {
      const int col = bn * 128 + wn + j * 16 + cc;
      const float bb = biasf[col];
#pragma unroll
      for (int r = 0; r < 4; ++r)
        gxstore(C + (size_t)(row0 + r) * 4096 + col, acc[i][j][r] + bb);
    }
  }
}

// ---------------------------------------------------------------------------
// Persistent recurrent kernel. 256 blocks x 256 threads, 64KB LDS.
// block: m = bid>>6 (batch tile of 16), g = bid&63 (16 h-cols -> 64 gate cols).
template <typename GT>
__global__ __launch_bounds__(256, 1) void k_lstm(
    const u16* __restrict__ Whr,   // [64][64][1024]
    const GT* __restrict__ Gx,     // [32768][4096]
    u16* __restrict__ hbuf,        // [2][64][1024] bf16 (buf 0 zeroed)
    float* __restrict__ out,       // stacked [512][64][1024], hT, cT
    unsigned* __restrict__ flags) {// [4][64*32] zeroed (128B-padded flags)
  // double-buffered h tile: 2 x 16 rows x 1024 cols bf16, chunk-swizzled:
  // 16B chunk p of row r stored at LDS chunk p ^ (r&7) within the row.
  __shared__ u16 hl[2 * 16 * 1024];            // 64 KB
  const int tid = threadIdx.x;
  const int w = tid >> 6, l = tid & 63, q = l >> 4, cc = l & 15;
  const int m = blockIdx.x >> 6, g = blockIdx.x & 63;
  const int gate = cc & 3;
  const int hcol = g * 16 + w * 4 + (cc >> 2);
  const int gxcol = gate * 1024 + hcol;
  const int wcol = w * 16 + cc;                // this lane's B-frag column
  unsigned* gflag = flags + m * (64 * 32);

  // ---- Wh B-fragments resident in registers (128 VGPRs/lane) ----
  // bfr[kk] = whr[(g*64 + wcol)*1024 + kk*32 + q*8 .. +8]
  // (identical values to the r1 LDS-staged BFRAG(kk); verified passing in r3)
  s16x8 bfr[32];
  {
    const u16* src = Whr + (size_t)(g * 64 + wcol) * 1024 + q * 8;
#pragma unroll
    for (int kk = 0; kk < 32; ++kk)
      bfr[kk] = *(const s16x8*)(src + kk * 32);
  }

  // per-lane swizzled A-frag read offsets (u16 units, relative to buffer base)
  const int xbit = (cc >> 2) & 1;
  const int off0 = cc * 1024 + ((q ^ (cc & 3)) + 4 * xbit) * 8;       // even frags
  const int off1 = cc * 1024 + ((q ^ (cc & 3)) + 4 * (1 - xbit)) * 8; // odd frags

  // refill geometry: thread owns linear chunks c = s*256 + tid (s=0..7):
  //   row r = c>>7, col-chunk p = c&127; global source chunk = p ^ (r&7).
  auto refill = [&](int buf) {
    const u16* hsrc = hbuf + (size_t)buf * (B_ * H_) + (size_t)m * 16 * 1024;
    u64 vb[16];
#pragma unroll
    for (int s = 0; s < 8; ++s) {
      const int c = s * 256 + tid;
      const int r = c >> 7, p = c & 127;
      const u64* src = (const u64*)(hsrc + r * 1024 + (p ^ (r & 7)) * 8);
      vb[2 * s] = __hip_atomic_load(src, __ATOMIC_RELAXED, __HIP_MEMORY_SCOPE_AGENT);
      vb[2 * s + 1] =
          __hip_atomic_load(src + 1, __ATOMIC_RELAXED, __HIP_MEMORY_SCOPE_AGENT);
    }
    u16* dst = hl + buf * (16 * 1024);
#pragma unroll
    for (int s = 0; s < 8; ++s) {
      union { u64 u[2]; s16x8 v; } t2;
      t2.u[0] = vb[2 * s]; t2.u[1] = vb[2 * s + 1];
      *(s16x8*)(dst + (s * 256 + tid) * 8) = t2.v;
    }
  };

  float cst[4] = {0.f, 0.f, 0.f, 0.f};
  float hlast[4] = {0.f, 0.f, 0.f, 0.f};

  // prefetch Gx for t=0
  float gxv[4];
  {
    const GT* gp = Gx + (size_t)(m * 16 + q * 4) * 4096 + gxcol;
#pragma unroll
    for (int r = 0; r < 4; ++r) gxv[r] = gxload(gp + (size_t)r * 4096);
  }

  refill(0);            // h0 = 0 (hbuf[0] zeroed; visible via kernel boundary)
  __syncthreads();      // hl[0] ready

  int polldead = 0;

  for (int t = 0; t < T_; ++t) {
    const u16* hbase = hl + (t & 1) * (16 * 1024);
    f32x4 acc0 = {0.f, 0.f, 0.f, 0.f}, acc1 = {0.f, 0.f, 0.f, 0.f};
#pragma unroll
    for (int I = 0; I < 32; I += 2) {
      s16x8 a0 = *(const s16x8*)(hbase + off0 + (I >> 1) * 64);
      s16x8 a1 = *(const s16x8*)(hbase + off1 + (I >> 1) * 64);
      acc0 = __builtin_amdgcn_mfma_f32_16x16x32_bf16(a0, bfr[I], acc0, 0, 0, 0);
      acc1 = __builtin_amdgcn_mfma_f32_16x16x32_bf16(a1, bfr[I + 1], acc1, 0, 0, 0);
    }

    float v0[4];
#pragma unroll
    for (int r = 0; r < 4; ++r) {
      float x = acc0[r] + acc1[r] + gxv[r];
      v0[r] = (gate == 2) ? tanh_(x) : sigm(x);
    }
#pragma unroll
    for (int r = 0; r < 4; ++r) {
      float a0 = v0[r];
      float a1 = __shfl_xor(a0, 1);
      float a2 = __shfl_xor(a0, 2);
      float a3 = __shfl_xor(a1, 2);
      float fv = (gate == 0) ? a0 : (gate == 1) ? a1 : (gate == 2) ? a2 : a3;
      float iv = (gate == 0) ? a1 : (gate == 1) ? a0 : (gate == 2) ? a3 : a2;
      float gv = (gate == 0) ? a2 : (gate == 1) ? a3 : (gate == 2) ? a0 : a1;
      float ov = (gate == 0) ? a3 : (gate == 1) ? a2 : (gate == 2) ? a1 : a0;
      float cn = fv * cst[r] + iv * gv;
      cst[r] = cn;
      hlast[r] = ov * tanh_(cn);
    }

    const int nb = (t + 1) & 1;
    const bool last = (t + 1 == T_);

    if (!last) {
      // ---- h publish: relaxed/AGENT (sc1) stores ----
      if (gate == 0) {
        u16* hd = hbuf + (size_t)nb * (B_ * H_);
#pragma unroll
        for (int r = 0; r < 4; ++r) {
          const int row = m * 16 + q * 4 + r;
          __hip_atomic_store(hd + row * 1024 + hcol, f2bf(hlast[r]),
                             __ATOMIC_RELAXED, __HIP_MEMORY_SCOPE_AGENT);
        }
      }
      // all waves' sc1 stores drained (s_waitcnt vmcnt(0) before s_barrier)
      __syncthreads();
      if (tid == 0)
        __hip_atomic_store(&gflag[g * 32], (unsigned)(t + 1), __ATOMIC_RELAXED,
                           __HIP_MEMORY_SCOPE_AGENT);
    }

    // Gx prefetch for t+1 and stacked-h output: issue now, drain under poll
    float gxn[4];
    {
      const int tn = (t + 1) & 511;
      const GT* gp = Gx + (size_t)(tn * 64 + m * 16 + q * 4) * 4096 + gxcol;
#pragma unroll
      for (int r = 0; r < 4; ++r) gxn[r] = gxload(gp + (size_t)r * 4096);
    }
    if (gate == 0) {
#pragma unroll
      for (int r = 0; r < 4; ++r) {
        const int row = m * 16 + q * 4 + r;
        out[(size_t)(t * 64 + row) * 1024 + hcol] = hlast[r];
      }
    }

    if (!last) {
      // ---- ALL waves poll the 64 group flags (lane l -> flag l) ----
      if (!polldead) {
        const unsigned* fp = gflag + l * 32;
        for (unsigned it = 0;; ++it) {
          unsigned v = __hip_atomic_load(fp, __ATOMIC_RELAXED,
                                         __HIP_MEMORY_SCOPE_AGENT);
          if (__all(v > (unsigned)t)) break;
          if (it > (1u << 20)) { polldead = 1; break; }   // safety: no hangs
          __builtin_amdgcn_s_sleep(1);
        }
      }
      asm volatile("" ::: "memory");  // no refill-load hoisting above the poll
      refill(nb);                     // relaxed/AGENT loads see peer h directly
      __syncthreads();                // hl[nb] ready for t+1
    }

#pragma unroll
    for (int r = 0; r < 4; ++r) gxv[r] = gxn[r];
  }

  if (gate == 0) {
    float* hT = out + (size_t)T_ * B_ * H_;
    float* cT = hT + B_ * H_;
#pragma unroll
    for (int r = 0; r < 4; ++r) {
      const int row = m * 16 + q * 4 + r;
      hT[row * 1024 + hcol] = hlast[r];
      cT[row * 1024 + hcol] = cst[r];
    }
  }
}

// ---------------------------------------------------------------------------
extern "C" void kernel_launch(void* const* d_in, const int* in_sizes, int n_in,
                              void* d_out, int out_size, void* d_ws, size_t ws_size,
                              hipStream_t stream) {
  (void)in_sizes; (void)n_in; (void)out_size;
  const float* x   = (const float*)d_in[0];
  const float* Wf  = (const float*)d_in[1];
  const float* bf_ = (const float*)d_in[2];
  const float* Wi  = (const float*)d_in[3];
  const float* bi_ = (const float*)d_in[4];
  const float* Wg  = (const float*)d_in[5];
  const float* bg_ = (const float*)d_in[6];
  const float* Wo  = (const float*)d_in[7];
  const float* bo_ = (const float*)d_in[8];
  float* out = (float*)d_out;

  uint8_t* ws = (uint8_t*)d_ws;
  const size_t n_gx    = (size_t)MX_ * NG_;
  const size_t sz_xb   = (size_t)MX_ * 1024 * 2;   // 64 MB
  const size_t sz_wxt  = (size_t)4096 * 1024 * 2;  // 8 MB
  const size_t sz_whr  = (size_t)4096 * 1024 * 2;  // 8 MB
  const size_t sz_bias = 4096 * 4;
  const size_t sz_hbuf = (size_t)2 * 64 * 1024 * 2;  // 256 KB bf16
  const size_t sz_ctrl = (size_t)4 * 64 * 32 * 4 + 8192;  // padded flags + pad
  const size_t fixed = sz_xb + sz_wxt + sz_whr + sz_bias + sz_hbuf + sz_ctrl + 1024;
  const bool f32gx = ws_size >= fixed + n_gx * 4;  // fp32 Gx (512 MB) if it fits
  const size_t sz_gx = n_gx * (f32gx ? 4 : 2);

  size_t off = 0;
  uint8_t* p_gx   = ws;                  off += sz_gx;
  u16*     xb     = (u16*)(ws + off);    off += sz_xb;
  u16*     wxt    = (u16*)(ws + off);    off += sz_wxt;
  u16*     whr    = (u16*)(ws + off);    off += sz_whr;
  float*   biasf  = (float*)(ws + off);  off += sz_bias;
  u16*     hbuf   = (u16*)(ws + off);    off += sz_hbuf;
  unsigned* flags = (unsigned*)(ws + off);

  // zero h buffers (h0 = 0) + barrier flags (contiguous)
  hipMemsetAsync(hbuf, 0, sz_hbuf + sz_ctrl, stream);
  k_cast_x<<<(MX_ * 1024) / (256 * 8), 256, 0, stream>>>(x, xb);
  k_prep_w<<<4096, 256, 0, stream>>>(Wf, Wi, Wg, Wo, bf_, bi_, bg_, bo_, wxt, whr, biasf);
  if (f32gx) {
    k_gemm_gx<float><<<dim3(256, 32), 256, 0, stream>>>(xb, wxt, biasf, (float*)p_gx);
    k_lstm<float><<<256, 256, 0, stream>>>(whr, (const float*)p_gx, hbuf, out, flags);
  } else {
    k_gemm_gx<u16><<<dim3(256, 32), 256, 0, stream>>>(xb, wxt, biasf, (u16*)p_gx);
    k_lstm<u16><<<256, 256, 0, stream>>>(whr, (const u16*)p_gx, hbuf, out, flags);
  }
}